// Round 7
// baseline (539.720 us; speedup 1.0000x reference)
//
#include <hip/hip_runtime.h>

// Bond harmonic energy with scatter-add onto first atom of each bond.
// Strategy: repack xyz [N,3] -> ws as float4 [N,4] (aligned, 1 dwordx4 per
// gather instead of 3 dwords), then 2 bonds/thread with vectorized stream
// loads and per-bond atomicAdd.

__global__ void pad_xyz_kernel(const float* __restrict__ xyz,
                               float4* __restrict__ xyz4, int n_atoms) {
    int i = blockIdx.x * blockDim.x + threadIdx.x;
    if (i < n_atoms) {
        const float* p = xyz + (size_t)i * 3;
        xyz4[i] = make_float4(p[0], p[1], p[2], 0.0f);
    }
}

// Two bonds per thread.
__global__ void bond_energy2_kernel(const float4* __restrict__ xyz4,
                                    const int4* __restrict__ adj2,   // [E/2] = 2 bonds
                                    const float2* __restrict__ blen2,
                                    const float2* __restrict__ bpar2,
                                    float* __restrict__ out,
                                    int n_pairs) {
    int i = blockIdx.x * blockDim.x + threadIdx.x;
    if (i >= n_pairs) return;

    int4   ab = adj2[i];
    float2 bl = blen2[i];
    float2 bp = bpar2[i];

    float4 a0 = xyz4[ab.x];
    float4 a1 = xyz4[ab.y];
    float4 b0 = xyz4[ab.z];
    float4 b1 = xyz4[ab.w];

    float dx0 = a0.x - a1.x, dy0 = a0.y - a1.y, dz0 = a0.z - a1.z;
    float dx1 = b0.x - b1.x, dy1 = b0.y - b1.y, dz1 = b0.z - b1.z;

    float e0 = sqrtf(dx0 * dx0 + dy0 * dy0 + dz0 * dz0);
    float e1 = sqrtf(dx1 * dx1 + dy1 * dy1 + dz1 * dz1);

    float d0 = e0 - bl.x;
    float d1 = e1 - bl.y;
    float v0 = 0.5f * bp.x * d0 * d0;
    float v1 = 0.5f * bp.y * d1 * d1;

    atomicAdd(&out[ab.x], v0);
    atomicAdd(&out[ab.z], v1);
}

// Fallback (unpadded, 1 bond/thread) if ws is too small.
__global__ void bond_energy_kernel(const float* __restrict__ xyz,
                                   const int2* __restrict__ adj,
                                   const float* __restrict__ blen,
                                   const float* __restrict__ bpar,
                                   float* __restrict__ out,
                                   int n_bonds) {
    int i = blockIdx.x * blockDim.x + threadIdx.x;
    if (i >= n_bonds) return;
    int2 ab = adj[i];
    const float* p0 = xyz + (size_t)ab.x * 3;
    const float* p1 = xyz + (size_t)ab.y * 3;
    float dx = p0[0] - p1[0];
    float dy = p0[1] - p1[1];
    float dz = p0[2] - p1[2];
    float e = sqrtf(dx * dx + dy * dy + dz * dz);
    float d = e - blen[i];
    float v = 0.5f * bpar[i] * d * d;
    atomicAdd(&out[ab.x], v);
}

extern "C" void kernel_launch(void* const* d_in, const int* in_sizes, int n_in,
                              void* d_out, int out_size, void* d_ws, size_t ws_size,
                              hipStream_t stream) {
    const float* xyz  = (const float*)d_in[0];
    const int*   adj  = (const int*)d_in[1];
    const float* blen = (const float*)d_in[2];
    const float* bpar = (const float*)d_in[3];
    float* out = (float*)d_out;

    const int n_bonds = in_sizes[1] / 2;   // [E,2] flat
    const int n_atoms = in_sizes[0] / 3;   // [N,3] flat

    // out is poisoned with 0xAA before every timed launch — zero it.
    (void)hipMemsetAsync(d_out, 0, (size_t)out_size * sizeof(float), stream);

    const int block = 256;
    const size_t pad_bytes = (size_t)n_atoms * 4 * sizeof(float);

    if (ws_size >= pad_bytes && (n_bonds & 1) == 0) {
        float4* xyz4 = (float4*)d_ws;
        pad_xyz_kernel<<<(n_atoms + block - 1) / block, block, 0, stream>>>(
            xyz, xyz4, n_atoms);
        const int n_pairs = n_bonds / 2;
        bond_energy2_kernel<<<(n_pairs + block - 1) / block, block, 0, stream>>>(
            xyz4, (const int4*)adj, (const float2*)blen, (const float2*)bpar,
            out, n_pairs);
    } else {
        bond_energy_kernel<<<(n_bonds + block - 1) / block, block, 0, stream>>>(
            xyz, (const int2*)adj, blen, bpar, out, n_bonds);
    }
}